// Round 9
// baseline (189.582 us; speedup 1.0000x reference)
//
#include <hip/hip_runtime.h>

// B=64, D=512 (ZD=E), L=8192, NL=1000, fp32 in/out.
// SINGLE fused persistent kernel (grid 401) + one tiny memset node.
//   blocks 0..255   (kC): stage W_zlat tile->LDS bf16, spin on flag, MFMA GEMM,
//                         store out directly (A pre-scaled by s[b]).
//   blocks 256..400 (chain, cid=blk-256):
//     phase1: cid<128 layer1 split-K-8 -> P1 ; cid 128..143 u1 = w_proj + Wy2^T w_proj
//     phase2: cid<128 layer2 -> P2 ; 128..143 u0 = u1 + Wy1^T u1 ; 144 d2 scalar
//     phase3: cid<16  zz = sum P2 partials, s[b] = gather-dot + d2, zzs = bf16(zz*s)
//   barriers/flag: ws counters (memset each call), device-scope atomics +
//   __threadfence (L2 wb/inv) for cross-XCD visibility.
// R9 fix vs R8: zzs is 16384 FLOATS (65536 B), not 8192 — u1/u0/d2/cnt were
//   inside it and phase-3 stores clobbered the barrier counters. Layout fixed;
//   cnt cells isolated 128 B apart well past all data.
// Co-residency: LDS 32 KB union + __launch_bounds__(256,2) -> >=2 blocks/CU
//   -> capacity >=512 >= 401 blocks, so spin/barriers cannot deadlock.

#define BB 64
#define DD 512
#define LL 8192
#define NLBL 1000
#define PIT 68
#define NKC 256
#define NCHAIN 145

typedef __attribute__((ext_vector_type(8))) short short8;
typedef __attribute__((ext_vector_type(4))) float f32x4;

__device__ __forceinline__ unsigned short f2bf(float f) {
  unsigned u = __float_as_uint(f);
  return (unsigned short)((u + 0x7fffu + ((u >> 16) & 1u)) >> 16);   // RNE
}

__device__ __forceinline__ unsigned ld_agent(const unsigned* p) {
  return __hip_atomic_load(p, __ATOMIC_RELAXED, __HIP_MEMORY_SCOPE_AGENT);
}

// arrive-and-wait among the NCHAIN chain blocks (one cell per barrier, no reuse)
__device__ __forceinline__ void chain_barrier(unsigned* c) {
  __syncthreads();                 // drains this block's vmem before arrival
  if (threadIdx.x == 0) {
    __threadfence();               // release: make prior stores device-visible
    atomicAdd(c, 1u);
    while (ld_agent(c) < NCHAIN) __builtin_amdgcn_s_sleep(1);
    __threadfence();               // acquire: invalidate stale L1/L2
  }
  __syncthreads();
}

// ---------- matvec: vout = vin + W^T vin (one 32-wide e-chunk) ----------
__device__ __forceinline__ void matvec_block(char* SM, int eblk,
                                             const float* __restrict__ W,
                                             const float* __restrict__ vin,
                                             float* __restrict__ vout) {
  float* vl = (float*)SM;          // 512
  float* red = vl + DD;            // 256
  int tid = threadIdx.x;
  vl[tid] = vin[tid];
  vl[tid + 256] = vin[tid + 256];
  __syncthreads();
  int el = tid & 31, jg = tid >> 5;
  int e = eblk * 32 + el;
  float acc = 0.f;
  for (int j = jg; j < DD; j += 8)
    acc += W[j * DD + e] * vl[j];
  red[tid] = acc;
  __syncthreads();
  if (tid < 32) {
    float s = vl[eblk * 32 + tid];
#pragma unroll
    for (int g = 0; g < 8; ++g) s += red[g * 32 + tid];
    vout[eblk * 32 + tid] = s;
  }
}

// ---------- layer GEMM, split-K 8, plain partial stores (fp32) ----------
template <int FIRST>
__device__ __forceinline__ void layer_gemm(char* SM, int blk,
                                           const float* __restrict__ Xg,
                                           const float* __restrict__ Pin,
                                           const float* __restrict__ W,
                                           const float* __restrict__ bias,
                                           float* __restrict__ P) {
  float (*Xs)[PIT] = (float (*)[PIT])SM;                    // 64x68 = 17408 B
  float (*Ws)[PIT] = (float (*)[PIT])(SM + BB * PIT * 4);   // 32x68 =  8704 B
  int tid = threadIdx.x;
  int jt = blk >> 3, ks = blk & 7;
  int j0 = jt * 32, k0 = ks * 64;
#pragma unroll
  for (int i = 0; i < 4; ++i) {      // X tile 64x64
    int slot = tid + i * 256, row = slot >> 4, c4 = (slot & 15) * 4;
    float4 v;
    if (FIRST) {
      v = *(const float4*)&Xg[row * DD + k0 + c4];
    } else {
      v = float4{0.f, 0.f, 0.f, 0.f};
#pragma unroll
      for (int s = 0; s < 8; ++s) {
        float4 p = *(const float4*)&Pin[(s * BB + row) * DD + k0 + c4];
        v.x += p.x; v.y += p.y; v.z += p.z; v.w += p.w;
      }
    }
    *(float4*)&Xs[row][c4] = v;
  }
#pragma unroll
  for (int i = 0; i < 2; ++i) {      // W tile 32x64
    int slot = tid + i * 256, row = slot >> 4, c4 = (slot & 15) * 4;
    *(float4*)&Ws[row][c4] = *(const float4*)&W[(j0 + row) * DD + k0 + c4];
  }
  __syncthreads();
  int jl = tid & 15, bl = tid >> 4;
  float acc[4][2] = {};
#pragma unroll
  for (int k = 0; k < 64; k += 4) {
    float4 xv[4], wv[2];
#pragma unroll
    for (int i = 0; i < 4; ++i) xv[i] = *(const float4*)&Xs[bl + 16 * i][k];
#pragma unroll
    for (int u = 0; u < 2; ++u) wv[u] = *(const float4*)&Ws[jl + 16 * u][k];
#pragma unroll
    for (int i = 0; i < 4; ++i)
#pragma unroll
      for (int u = 0; u < 2; ++u)
        acc[i][u] += xv[i].x * wv[u].x + xv[i].y * wv[u].y +
                     xv[i].z * wv[u].z + xv[i].w * wv[u].w;
  }
#pragma unroll
  for (int i = 0; i < 4; ++i) {
    int b = bl + 16 * i;
#pragma unroll
    for (int u = 0; u < 2; ++u) {
      int jj = j0 + jl + 16 * u;
      float v = acc[i][u];
      if (ks == 0) {
        float xr;
        if (FIRST) {
          xr = Xg[b * DD + jj];
        } else {
          xr = 0.f;
#pragma unroll
          for (int s = 0; s < 8; ++s) xr += Pin[(s * BB + b) * DD + jj];
        }
        v += xr + bias[jj];
      }
      P[(ks * BB + b) * DD + jj] = v;
    }
  }
}

// =============================== mega kernel ===============================
__global__ __launch_bounds__(256, 2) void mega(
    const float* __restrict__ z, const float* __restrict__ Wz1,
    const float* __restrict__ bz1, const float* __restrict__ Wz2,
    const float* __restrict__ bz2, const float* __restrict__ Wy1,
    const float* __restrict__ by1, const float* __restrict__ Wy2,
    const float* __restrict__ by2, const float* __restrict__ w_proj,
    const float* __restrict__ W_yemb, const float* __restrict__ b_yemb,
    const int* __restrict__ y, const float* __restrict__ W_zlat,
    float* __restrict__ P1, float* __restrict__ P2,
    unsigned short* __restrict__ zzs, float* __restrict__ u1,
    float* __restrict__ u0, float* __restrict__ d2,
    unsigned* __restrict__ cnt, float* __restrict__ out) {
  __shared__ __align__(16) char SM[32768];
  int blk = blockIdx.x, tid = threadIdx.x;

  if (blk < NKC) {
    // ================= kC: W staging overlaps the whole chain =================
    unsigned short* Bs = (unsigned short*)SM;      // 32 rows x 512 k bf16 = 32 KB
    int l0 = blk * 32;
#pragma unroll
    for (int i = 0; i < 8; ++i) {
      int gi = tid + i * 256;                      // 0..2047 granules (16B)
      int row = gi >> 6, c = gi & 63;
      const float* src = &W_zlat[(size_t)(l0 + row) * DD + c * 8];
      float4 v0 = *(const float4*)src;
      float4 v1 = *(const float4*)(src + 4);
      short8 h = {(short)f2bf(v0.x), (short)f2bf(v0.y), (short)f2bf(v0.z),
                  (short)f2bf(v0.w), (short)f2bf(v1.x), (short)f2bf(v1.y),
                  (short)f2bf(v1.z), (short)f2bf(v1.w)};
      *(short8*)&Bs[row * DD + ((c ^ (row & 7)) << 3)] = h;
    }
    if (tid == 0) {                                // wait for chain phase-3
      while (ld_agent(&cnt[64]) < NCHAIN) __builtin_amdgcn_s_sleep(2);
      __threadfence();                             // acquire zzs
    }
    __syncthreads();                               // also orders Bs writes
    int wave = tid >> 6, lane = tid & 63, quad = lane >> 4, l15 = lane & 15;
    const unsigned short* arow = zzs + (wave * 16 + l15) * DD + quad * 8;
    int brow0 = l15, brow1 = 16 + l15;
    f32x4 acc0 = {}, acc1 = {};
    short8 apf[4];
#pragma unroll
    for (int p = 0; p < 4; ++p) apf[p] = *(const short8*)(arow + p * 32);
#pragma unroll
    for (int kc = 0; kc < 4; ++kc) {
      short8 cur[4] = {apf[0], apf[1], apf[2], apf[3]};
      if (kc < 3) {
#pragma unroll
        for (int p = 0; p < 4; ++p)
          apf[p] = *(const short8*)(arow + (kc + 1) * 128 + p * 32);
      }
#pragma unroll
      for (int s = 0; s < 4; ++s) {
        int c = kc * 16 + s * 4 + quad;            // k-granule column 0..63
        short8 b0 = *(const short8*)&Bs[brow0 * DD + ((c ^ (brow0 & 7)) << 3)];
        short8 b1 = *(const short8*)&Bs[brow1 * DD + ((c ^ (brow1 & 7)) << 3)];
        acc0 = __builtin_amdgcn_mfma_f32_16x16x32_bf16(cur[s], b0, acc0, 0, 0, 0);
        acc1 = __builtin_amdgcn_mfma_f32_16x16x32_bf16(cur[s], b1, acc1, 0, 0, 0);
      }
    }
#pragma unroll
    for (int reg = 0; reg < 4; ++reg) {            // b = wave*16 + quad*4 + reg
      int b = wave * 16 + quad * 4 + reg;
      size_t o = (size_t)b * LL + l0;
      out[o + l15] = acc0[reg];
      out[o + 16 + l15] = acc1[reg];
    }
    return;
  }

  // ================================ chain ===================================
  int cid = blk - NKC;                             // 0..144
  // ---- phase 1: layer1 -> P1 ; u1 matvec
  if (cid < 128)      layer_gemm<1>(SM, cid, z, nullptr, Wz1, bz1, P1);
  else if (cid < 144) matvec_block(SM, cid - 128, Wy2, w_proj, u1);
  chain_barrier(&cnt[0]);
  // ---- phase 2: layer2 -> P2 ; u0 matvec ; d2 scalar
  if (cid < 128) {
    layer_gemm<0>(SM, cid, nullptr, P1, Wz2, bz2, P2);
  } else if (cid < 144) {
    matvec_block(SM, cid - 128, Wy1, u1, u0);
  } else {
    float* red = (float*)SM;
    float p = by1[tid] * u1[tid] + by2[tid] * w_proj[tid] +
              by1[tid + 256] * u1[tid + 256] + by2[tid + 256] * w_proj[tid + 256];
    red[tid] = p;
    __syncthreads();
    if (tid < 64) {
      float s = red[tid] + red[tid + 64] + red[tid + 128] + red[tid + 192];
#pragma unroll
      for (int d = 32; d; d >>= 1) s += __shfl_down(s, d, 64);
      if (tid == 0) d2[0] = s;
    }
  }
  chain_barrier(&cnt[32]);
  // ---- phase 3: zz reduce + s-gather + A-side scale -> zzs (bf16)
  if (cid < 16) {
    int bloc = tid >> 6, lane = tid & 63;
    int bb = cid * 4 + bloc;
    int yb = y[bb];
    int e0 = lane * 8;
    float4 ua = *(const float4*)&u0[e0];
    float4 ub = *(const float4*)&u0[e0 + 4];
    float4 ba = *(const float4*)&b_yemb[e0];
    float4 bb4 = *(const float4*)&b_yemb[e0 + 4];
    const float* wy = W_yemb + yb;
    float sg = (wy[(size_t)(e0 + 0) * NLBL] + ba.x) * ua.x +
               (wy[(size_t)(e0 + 1) * NLBL] + ba.y) * ua.y +
               (wy[(size_t)(e0 + 2) * NLBL] + ba.z) * ua.z +
               (wy[(size_t)(e0 + 3) * NLBL] + ba.w) * ua.w +
               (wy[(size_t)(e0 + 4) * NLBL] + bb4.x) * ub.x +
               (wy[(size_t)(e0 + 5) * NLBL] + bb4.y) * ub.y +
               (wy[(size_t)(e0 + 6) * NLBL] + bb4.z) * ub.z +
               (wy[(size_t)(e0 + 7) * NLBL] + bb4.w) * ub.w;
#pragma unroll
    for (int d = 32; d; d >>= 1) sg += __shfl_down(sg, d, 64);
    float* s4 = (float*)SM;
    if (lane == 0) s4[bloc] = sg + d2[0];
    __syncthreads();
    float sv = s4[bloc];
    int eo = cid * 2048 + tid * 8;                 // row b = cid*4 + (tid>>6)
    float4 a0 = {0.f, 0.f, 0.f, 0.f}, a1 = {0.f, 0.f, 0.f, 0.f};
#pragma unroll
    for (int s = 0; s < 8; ++s) {
      const float* p = P2 + s * (BB * DD) + eo;
      float4 x = *(const float4*)p;
      float4 q = *(const float4*)(p + 4);
      a0.x += x.x; a0.y += x.y; a0.z += x.z; a0.w += x.w;
      a1.x += q.x; a1.y += q.y; a1.z += q.z; a1.w += q.w;
    }
    short8 h = {(short)f2bf(a0.x * sv), (short)f2bf(a0.y * sv),
                (short)f2bf(a0.z * sv), (short)f2bf(a0.w * sv),
                (short)f2bf(a1.x * sv), (short)f2bf(a1.y * sv),
                (short)f2bf(a1.z * sv), (short)f2bf(a1.w * sv)};
    *(short8*)&zzs[eo] = h;
  }
  chain_barrier(&cnt[64]);                         // releases the kC blocks
}

extern "C" void kernel_launch(void* const* d_in, const int* in_sizes, int n_in,
                              void* d_out, int out_size, void* d_ws, size_t ws_size,
                              hipStream_t stream) {
  const float* z      = (const float*)d_in[0];
  const int*   y      = (const int*)  d_in[1];
  const float* W_yemb = (const float*)d_in[2];
  const float* b_yemb = (const float*)d_in[3];
  const float* Wy1    = (const float*)d_in[4];
  const float* by1    = (const float*)d_in[5];
  const float* Wy2    = (const float*)d_in[6];
  const float* by2    = (const float*)d_in[7];
  const float* Wz1    = (const float*)d_in[8];
  const float* bz1    = (const float*)d_in[9];
  const float* Wz2    = (const float*)d_in[10];
  const float* bz2    = (const float*)d_in[11];
  const float* W_zlat = (const float*)d_in[12];
  const float* w_proj = (const float*)d_in[13];

  float* ws = (float*)d_ws;
  float* P1 = ws;                                  // floats [0      .. 262144)
  float* P2 = ws + 262144;                         // floats [262144 .. 524288)
  unsigned short* zzs = (unsigned short*)(ws + 524288);  // 32768 shorts = 16384 floats
  float* u1 = ws + 540672;                         // [512]   (= 524288 + 16384)
  float* u0 = ws + 541184;                         // [512]
  float* d2 = ws + 541696;                         // [1]
  unsigned* cnt = (unsigned*)(ws + 541712);        // 3 cells at +0,+32,+64 (128B apart)
  float* out = (float*)d_out;

  hipMemsetAsync(cnt, 0, 384, stream);             // zero barrier cells (graph node)
  mega<<<NKC + NCHAIN, 256, 0, stream>>>(
      z, Wz1, bz1, Wz2, bz2, Wy1, by1, Wy2, by2, w_proj, W_yemb, b_yemb, y,
      W_zlat, P1, P2, zzs, u1, u0, d2, cnt, out);
}

// Round 10
// 143.379 us; speedup vs baseline: 1.3222x; 1.3222x over previous
//
#include <hip/hip_runtime.h>

// B=64, D=512 (ZD=E), L=8192, NL=1000, fp32 in/out. No atomics. 4 dispatches.
// out[b,l] = s[b] * dot(zz[b,:], W_zlat[l,:])
//   kA: layer1 split-K-8 -> P1 ; u1 = w_proj + Wy2^T w_proj
//   kB: layer2 split-K-8 -> P2 ; u0 = u1 + Wy1^T u1 ; d2 = by1.u1 + by2.w_proj
//   kZ: 16 blocks, each owns 4 b-rows: s[b] = gather-dot(W_yemb[:,y[b]]+b_yemb, u0)
//       + d2 ; zzs[b,:] = bf16( (sum_ks P2[ks][b][:]) * s[b] )   (scale on A side)
//   kC: 512 blocks, l-tile 16, full K=512. B tile (16x512 fp32->bf16) in LDS
//       (16 KB -> >=2 blocks/CU for staging/compute overlap); A-fragments read
//       DIRECTLY from zzs (64 KB, L1/L2-resident) — path proven in R9's mega.
// R9 lesson: grid-wide fusion costs ~100 µs in device-scope fence L2-writebacks
// (buffer_wbl2 per barrier) on non-coherent XCDs — 4 dispatches is the floor.

#define BB 64
#define DD 512
#define LL 8192
#define NLBL 1000
#define PIT 68   // (kA/kB only) LDS pitch

typedef __attribute__((ext_vector_type(8))) short short8;
typedef __attribute__((ext_vector_type(4))) float f32x4;

__device__ __forceinline__ unsigned short f2bf(float f) {
  unsigned u = __float_as_uint(f);
  return (unsigned short)((u + 0x7fffu + ((u >> 16) & 1u)) >> 16);   // RNE
}

// ---------- matvec: vout = vin + W^T vin (one 32-wide e-chunk) ----------
__device__ __forceinline__ void matvec_block(int eblk, const float* __restrict__ W,
                                             const float* __restrict__ vin,
                                             float* __restrict__ vout) {
  __shared__ float vl[DD];
  __shared__ float red[256];
  int tid = threadIdx.x;
  vl[tid] = vin[tid];
  vl[tid + 256] = vin[tid + 256];
  __syncthreads();
  int el = tid & 31, jg = tid >> 5;
  int e = eblk * 32 + el;
  float acc = 0.f;
  for (int j = jg; j < DD; j += 8)
    acc += W[j * DD + e] * vl[j];
  red[tid] = acc;
  __syncthreads();
  if (tid < 32) {
    float s = vl[eblk * 32 + tid];
#pragma unroll
    for (int g = 0; g < 8; ++g) s += red[g * 32 + tid];
    vout[eblk * 32 + tid] = s;
  }
}

// ---------- layer GEMM, split-K 8, plain partial stores (fp32) ----------
template <int FIRST>
__device__ __forceinline__ void layer_gemm(int blk, const float* __restrict__ Xg,
                                           const float* __restrict__ Pin,
                                           const float* __restrict__ W,
                                           const float* __restrict__ bias,
                                           float* __restrict__ P) {
  __shared__ __align__(16) float Xs[BB][PIT];
  __shared__ __align__(16) float Ws[32][PIT];
  int tid = threadIdx.x;
  int jt = blk >> 3, ks = blk & 7;
  int j0 = jt * 32, k0 = ks * 64;
#pragma unroll
  for (int i = 0; i < 4; ++i) {      // X tile 64x64
    int slot = tid + i * 256, row = slot >> 4, c4 = (slot & 15) * 4;
    float4 v;
    if (FIRST) {
      v = *(const float4*)&Xg[row * DD + k0 + c4];
    } else {
      v = float4{0.f, 0.f, 0.f, 0.f};
#pragma unroll
      for (int s = 0; s < 8; ++s) {
        float4 p = *(const float4*)&Pin[(s * BB + row) * DD + k0 + c4];
        v.x += p.x; v.y += p.y; v.z += p.z; v.w += p.w;
      }
    }
    *(float4*)&Xs[row][c4] = v;
  }
#pragma unroll
  for (int i = 0; i < 2; ++i) {      // W tile 32x64
    int slot = tid + i * 256, row = slot >> 4, c4 = (slot & 15) * 4;
    *(float4*)&Ws[row][c4] = *(const float4*)&W[(j0 + row) * DD + k0 + c4];
  }
  __syncthreads();
  int jl = tid & 15, bl = tid >> 4;
  float acc[4][2] = {};
#pragma unroll
  for (int k = 0; k < 64; k += 4) {
    float4 xv[4], wv[2];
#pragma unroll
    for (int i = 0; i < 4; ++i) xv[i] = *(const float4*)&Xs[bl + 16 * i][k];
#pragma unroll
    for (int u = 0; u < 2; ++u) wv[u] = *(const float4*)&Ws[jl + 16 * u][k];
#pragma unroll
    for (int i = 0; i < 4; ++i)
#pragma unroll
      for (int u = 0; u < 2; ++u)
        acc[i][u] += xv[i].x * wv[u].x + xv[i].y * wv[u].y +
                     xv[i].z * wv[u].z + xv[i].w * wv[u].w;
  }
#pragma unroll
  for (int i = 0; i < 4; ++i) {
    int b = bl + 16 * i;
#pragma unroll
    for (int u = 0; u < 2; ++u) {
      int jj = j0 + jl + 16 * u;
      float v = acc[i][u];
      if (ks == 0) {
        float xr;
        if (FIRST) {
          xr = Xg[b * DD + jj];
        } else {
          xr = 0.f;
#pragma unroll
          for (int s = 0; s < 8; ++s) xr += Pin[(s * BB + b) * DD + jj];
        }
        v += xr + bias[jj];
      }
      P[(ks * BB + b) * DD + jj] = v;
    }
  }
}

// ---------------- kA: layer1 partials + u1 matvec ----------------
__global__ __launch_bounds__(256) void kA(const float* __restrict__ z,
                                          const float* __restrict__ Wz1,
                                          const float* __restrict__ bz1,
                                          float* __restrict__ P1,
                                          const float* __restrict__ Wy2,
                                          const float* __restrict__ w_proj,
                                          float* __restrict__ u1) {
  int blk = blockIdx.x;
  if (blk < 128) layer_gemm<1>(blk, z, nullptr, Wz1, bz1, P1);
  else           matvec_block(blk - 128, Wy2, w_proj, u1);
}

// ---------------- kB: layer2 partials + u0 matvec + d2 scalar ----------------
__global__ __launch_bounds__(256) void kB(const float* __restrict__ P1,
                                          const float* __restrict__ Wz2,
                                          const float* __restrict__ bz2,
                                          float* __restrict__ P2,
                                          const float* __restrict__ Wy1,
                                          const float* __restrict__ u1,
                                          float* __restrict__ u0,
                                          const float* __restrict__ by1,
                                          const float* __restrict__ by2,
                                          const float* __restrict__ w_proj,
                                          float* __restrict__ d2) {
  int blk = blockIdx.x;
  if (blk < 128) {
    layer_gemm<0>(blk, nullptr, P1, Wz2, bz2, P2);
  } else if (blk < 144) {
    matvec_block(blk - 128, Wy1, u1, u0);
  } else {
    __shared__ float red[256];
    int tid = threadIdx.x;
    float p = by1[tid] * u1[tid] + by2[tid] * w_proj[tid] +
              by1[tid + 256] * u1[tid + 256] + by2[tid + 256] * w_proj[tid + 256];
    red[tid] = p;
    __syncthreads();
    if (tid < 64) {
      float s = red[tid] + red[tid + 64] + red[tid + 128] + red[tid + 192];
#pragma unroll
      for (int d = 32; d; d >>= 1) s += __shfl_down(s, d, 64);
      if (tid == 0) d2[0] = s;
    }
  }
}

// ---------------- kZ: s-gather + reduce P2 -> scaled bf16 zzs ----------------
// 16 blocks; block cid owns b rows cid*4 .. cid*4+3 (wave bloc = one b each).
// (ported from R9 mega phase-3, numerically proven)
__global__ __launch_bounds__(256) void kZ(const float* __restrict__ P2,
                                          unsigned short* __restrict__ zzs,
                                          const float* __restrict__ W_yemb,
                                          const float* __restrict__ b_yemb,
                                          const int* __restrict__ y,
                                          const float* __restrict__ u0,
                                          const float* __restrict__ d2) {
  __shared__ float s4[4];
  int cid = blockIdx.x, tid = threadIdx.x;
  int bloc = tid >> 6, lane = tid & 63;
  int bb = cid * 4 + bloc;
  int yb = y[bb];
  int e0 = lane * 8;
  float4 ua = *(const float4*)&u0[e0];
  float4 ub = *(const float4*)&u0[e0 + 4];
  float4 ba = *(const float4*)&b_yemb[e0];
  float4 bb4 = *(const float4*)&b_yemb[e0 + 4];
  const float* wy = W_yemb + yb;
  float sg = (wy[(size_t)(e0 + 0) * NLBL] + ba.x) * ua.x +
             (wy[(size_t)(e0 + 1) * NLBL] + ba.y) * ua.y +
             (wy[(size_t)(e0 + 2) * NLBL] + ba.z) * ua.z +
             (wy[(size_t)(e0 + 3) * NLBL] + ba.w) * ua.w +
             (wy[(size_t)(e0 + 4) * NLBL] + bb4.x) * ub.x +
             (wy[(size_t)(e0 + 5) * NLBL] + bb4.y) * ub.y +
             (wy[(size_t)(e0 + 6) * NLBL] + bb4.z) * ub.z +
             (wy[(size_t)(e0 + 7) * NLBL] + bb4.w) * ub.w;
#pragma unroll
  for (int d = 32; d; d >>= 1) sg += __shfl_down(sg, d, 64);
  if (lane == 0) s4[bloc] = sg + d2[0];
  __syncthreads();
  float sv = s4[bloc];
  int eo = cid * 2048 + tid * 8;                 // row of eo == bb by layout
  float4 a0 = {0.f, 0.f, 0.f, 0.f}, a1 = {0.f, 0.f, 0.f, 0.f};
#pragma unroll
  for (int s = 0; s < 8; ++s) {
    const float* p = P2 + s * (BB * DD) + eo;
    float4 x = *(const float4*)p;
    float4 q = *(const float4*)(p + 4);
    a0.x += x.x; a0.y += x.y; a0.z += x.z; a0.w += x.w;
    a1.x += q.x; a1.y += q.y; a1.z += q.z; a1.w += q.w;
  }
  short8 h = {(short)f2bf(a0.x * sv), (short)f2bf(a0.y * sv),
              (short)f2bf(a0.z * sv), (short)f2bf(a0.w * sv),
              (short)f2bf(a1.x * sv), (short)f2bf(a1.y * sv),
              (short)f2bf(a1.z * sv), (short)f2bf(a1.w * sv)};
  *(short8*)&zzs[eo] = h;
}

// ---------------- kC: out[b,l] = dot(zzs[b,:], W[l,:])  (zzs pre-scaled) -----
// 512 blocks, l-tile 16 (l0 = blk*16), full K=512.
// LDS: Bs 16x512 bf16 = 16 KB only -> >=2 blocks/CU. XOR-granule swizzle
// phys = c ^ (row & 7) (16-B granules). A-fragments straight from zzs global
// (64 KB, L1/L2-hot). Wave w owns m-tile w (b = w*16+quad*4+reg), one n-tile.
__global__ __launch_bounds__(256) void kC(const unsigned short* __restrict__ zzs,
                                          const float* __restrict__ W,
                                          float* __restrict__ out) {
  __shared__ __align__(16) unsigned short Bs[16 * 512];
  int tid = threadIdx.x;
  int l0 = blockIdx.x * 16;
#pragma unroll
  for (int i = 0; i < 4; ++i) {      // 1024 8-float granules of W
    int gi = tid + i * 256, row = gi >> 6, c = gi & 63;
    const float* src = &W[(size_t)(l0 + row) * DD + c * 8];
    float4 v0 = *(const float4*)src;
    float4 v1 = *(const float4*)(src + 4);
    short8 h = {(short)f2bf(v0.x), (short)f2bf(v0.y), (short)f2bf(v0.z),
                (short)f2bf(v0.w), (short)f2bf(v1.x), (short)f2bf(v1.y),
                (short)f2bf(v1.z), (short)f2bf(v1.w)};
    *(short8*)&Bs[row * DD + ((c ^ (row & 7)) << 3)] = h;
  }
  __syncthreads();
  int wave = tid >> 6, lane = tid & 63, quad = lane >> 4, l15 = lane & 15;
  const unsigned short* arow = zzs + (wave * 16 + l15) * DD + quad * 8;
  f32x4 acc = {};
  short8 apf[4];
#pragma unroll
  for (int p = 0; p < 4; ++p) apf[p] = *(const short8*)(arow + p * 32);
#pragma unroll
  for (int kc = 0; kc < 4; ++kc) {
    short8 cur[4] = {apf[0], apf[1], apf[2], apf[3]};
    if (kc < 3) {
#pragma unroll
      for (int p = 0; p < 4; ++p)
        apf[p] = *(const short8*)(arow + (kc + 1) * 128 + p * 32);
    }
#pragma unroll
    for (int s = 0; s < 4; ++s) {
      int c = kc * 16 + s * 4 + quad;            // k-granule column 0..63
      short8 bf = *(const short8*)&Bs[l15 * DD + ((c ^ (l15 & 7)) << 3)];
      acc = __builtin_amdgcn_mfma_f32_16x16x32_bf16(cur[s], bf, acc, 0, 0, 0);
    }
  }
#pragma unroll
  for (int reg = 0; reg < 4; ++reg) {            // b = wave*16 + quad*4 + reg
    int b = wave * 16 + quad * 4 + reg;
    out[(size_t)b * LL + l0 + l15] = acc[reg];
  }
}

extern "C" void kernel_launch(void* const* d_in, const int* in_sizes, int n_in,
                              void* d_out, int out_size, void* d_ws, size_t ws_size,
                              hipStream_t stream) {
  const float* z      = (const float*)d_in[0];
  const int*   y      = (const int*)  d_in[1];
  const float* W_yemb = (const float*)d_in[2];
  const float* b_yemb = (const float*)d_in[3];
  const float* Wy1    = (const float*)d_in[4];
  const float* by1    = (const float*)d_in[5];
  const float* Wy2    = (const float*)d_in[6];
  const float* by2    = (const float*)d_in[7];
  const float* Wz1    = (const float*)d_in[8];
  const float* bz1    = (const float*)d_in[9];
  const float* Wz2    = (const float*)d_in[10];
  const float* bz2    = (const float*)d_in[11];
  const float* W_zlat = (const float*)d_in[12];
  const float* w_proj = (const float*)d_in[13];

  float* ws = (float*)d_ws;
  float* P1 = ws;                                  // floats [0      .. 262144)
  float* P2 = ws + 262144;                         // floats [262144 .. 524288)
  unsigned short* zzs = (unsigned short*)(ws + 524288);  // 32768 shorts (16384 f)
  float* u1 = ws + 540672;                         // [512]
  float* u0 = ws + 541184;                         // [512]
  float* d2 = ws + 541696;                         // [1]
  float* out = (float*)d_out;

  kA<<<144, 256, 0, stream>>>(z, Wz1, bz1, P1, Wy2, w_proj, u1);
  kB<<<145, 256, 0, stream>>>(P1, Wz2, bz2, P2, Wy1, u1, u0, by1, by2, w_proj, d2);
  kZ<<<16, 256, 0, stream>>>(P2, zzs, W_yemb, b_yemb, y, u0, d2);
  kC<<<512, 256, 0, stream>>>(zzs, W_zlat, out);
}